// Round 2
// baseline (143.021 us; speedup 1.0000x reference)
//
#include <hip/hip_runtime.h>
#include <math.h>

// Problem constants (match reference).
constexpr int kN      = 5;
constexpr int kB      = 1048576;
constexpr int kBN     = kB * kN;        // 5,242,880 floats per output plane
constexpr int kBN4    = kBN / 4;        // 1,310,720 float4 groups per plane
constexpr int kSteps  = 10;
constexpr int kThreads = 256;
constexpr int kBlocks  = kB / (4 * kThreads);   // 1024: one 4-row chunk per thread

__device__ __forceinline__ float softplus_f(float x)
{
    // stable: max(x,0) + log1p(exp(-|x|))
    return fmaxf(x, 0.f) + log1pf(expf(-fabsf(x)));
}

// One dynamics evaluation. Lane i (i = lane for lanes 0..4, else mirror of 0)
// owns oscillator i; shuffles read only lanes 0..4, which hold real state.
__device__ __forceinline__ void cpg_dynamics(float r, float rd, float th,
                                             float mu, float a,
                                             const float wr[kN], const float ph[kN],
                                             float freq, float& rdd, float& thd)
{
    rdd = a * (a * 0.25f * (mu - r) - rd);
    float coup = 0.f;
#pragma unroll
    for (int j = 0; j < kN; ++j) {
        float th_j = __shfl(th, j);
        float r_j  = __shfl(r, j);
        coup = __builtin_fmaf(wr[j] * __sinf(th_j - th - ph[j]), r_j, coup);
    }
    thd = freq + coup;
}

__global__ __launch_bounds__(kThreads)
void ijspeert_kernel(const float* __restrict__ t,
                     const float* __restrict__ dt_p,
                     const float* __restrict__ mu_p,
                     const float* __restrict__ a_p,
                     const float* __restrict__ w_p,
                     const float* __restrict__ phi_p,
                     const float* __restrict__ freq_p,
                     const float* __restrict__ amp_p,
                     const float* __restrict__ phase_p,
                     const float* __restrict__ std_p,
                     float* __restrict__ out)
{
    const int tid  = blockIdx.x * kThreads + (int)threadIdx.x;
    const int lane = (int)(threadIdx.x & 63u);
    const int i    = (lane < kN) ? lane : 0;

    // ---- Per-lane oscillator params (lanes 0..4 live), broadcast via shfl ----
    const float pi = 3.14159265358979323846f;
    const float fr = freq_p[i];                      // raw frequency (used by ODE)
    const float my_w2  = 2.f * pi * softplus_f(fr);  // 2*pi*true_frequency
    const float my_amp = tanhf(amp_p[i]) * ((i & 1) ? pi : 0.5f * pi);  // RANGE pattern
    const float my_ph  = softplus_f(phase_p[i]);
    const float my_sd  = std_p[i];

    float amp[kN], w2[kN], pp[kN], sd[kN];
#pragma unroll
    for (int j = 0; j < kN; ++j) {
        amp[j] = __shfl(my_amp, j);
        w2[j]  = __shfl(my_w2,  j);
        pp[j]  = __shfl(my_ph,  j);
        sd[j]  = __shfl(my_sd,  j);
    }

    float4* o = reinterpret_cast<float4*>(out);
    const int q0 = tid * 5;   // this thread's first float4 within each plane

    // ---- Phase A: mu + std planes (independent of the ODE solve) ----
    {
        const float4 tv = reinterpret_cast<const float4*>(t)[tid];
        const float tb[4] = {tv.x, tv.y, tv.z, tv.w};

        float4 m4[5];
        float* m = reinterpret_cast<float*>(m4);
#pragma unroll
        for (int bb = 0; bb < 4; ++bb)
#pragma unroll
            for (int j = 0; j < kN; ++j)
                m[bb * 5 + j] = amp[j] * __sinf(__builtin_fmaf(w2[j], tb[bb], pp[j]));
#pragma unroll
        for (int k = 0; k < 5; ++k) o[q0 + k] = m4[k];

        float4 s4[5];
        float* s = reinterpret_cast<float*>(s4);
#pragma unroll
        for (int k = 0; k < 20; ++k) s[k] = sd[k % 5];
#pragma unroll
        for (int k = 0; k < 5; ++k) o[kBN4 + q0 + k] = s4[k];
    }

    // ---- ODE solve: every wave redundantly (latency-bound, hides across
    //      waves; phase-A stores drain to HBM meanwhile; no barrier/LDS) ----
    float wr[kN], ph[kN];
#pragma unroll
    for (int j = 0; j < kN; ++j) {
        wr[j] = w_p[i * kN + j];
        ph[j] = phi_p[i * kN + j];
    }
    const float dt = dt_p[0];
    const float mu = mu_p[i];
    const float a  = a_p[i];

    float r = 0.f, rd = 0.f, th = 0.f;
    for (int s = 0; s < kSteps; ++s) {
        float rdd1, td1, rdd2, td2, rdd3, td3, rdd4, td4;
        cpg_dynamics(r, rd, th, mu, a, wr, ph, fr, rdd1, td1);
        const float k1_r = rd, k1_rd = rdd1, k1_t = td1;
        cpg_dynamics(r + 0.5f * dt * k1_r, rd + 0.5f * dt * k1_rd,
                     th + 0.5f * dt * k1_t, mu, a, wr, ph, fr, rdd2, td2);
        const float k2_r = rd + 0.5f * dt * k1_rd, k2_rd = rdd2, k2_t = td2;
        cpg_dynamics(r + 0.5f * dt * k2_r, rd + 0.5f * dt * k2_rd,
                     th + 0.5f * dt * k2_t, mu, a, wr, ph, fr, rdd3, td3);
        const float k3_r = rd + 0.5f * dt * k2_rd, k3_rd = rdd3, k3_t = td3;
        cpg_dynamics(r + dt * k3_r, rd + dt * k3_rd,
                     th + dt * k3_t, mu, a, wr, ph, fr, rdd4, td4);
        const float k4_r = rd + dt * k3_rd, k4_rd = rdd4, k4_t = td4;
        const float c = dt * (1.f / 6.f);
        r  += c * (k1_r  + 2.f * k2_r  + 2.f * k3_r  + k4_r);
        rd += c * (k1_rd + 2.f * k2_rd + 2.f * k3_rd + k4_rd);
        th += c * (k1_t  + 2.f * k2_t  + 2.f * k3_t  + k4_t);
    }

    // ---- Phase B: r + theta planes ----
    float rr[kN], tt[kN];
#pragma unroll
    for (int j = 0; j < kN; ++j) { rr[j] = __shfl(r, j); tt[j] = __shfl(th, j); }

    float4 r4[5], t4[5];
    float* rp = reinterpret_cast<float*>(r4);
    float* tp = reinterpret_cast<float*>(t4);
#pragma unroll
    for (int k = 0; k < 20; ++k) { rp[k] = rr[k % 5]; tp[k] = tt[k % 5]; }
#pragma unroll
    for (int k = 0; k < 5; ++k) o[2 * kBN4 + q0 + k] = r4[k];
#pragma unroll
    for (int k = 0; k < 5; ++k) o[3 * kBN4 + q0 + k] = t4[k];
}

extern "C" void kernel_launch(void* const* d_in, const int* in_sizes, int n_in,
                              void* d_out, int out_size, void* d_ws, size_t ws_size,
                              hipStream_t stream)
{
    // setup_inputs order:
    // 0: obs [B,10] (unused)   1: t [B]        2: dt [1]
    // 3: mu_p [N]  4: a [N]    5: w [N,N]      6: phi [N,N]
    // 7: frequencies [N]  8: amplitudes [N]  9: phases [N]  10: std [N]
    const float* t      = (const float*)d_in[1];
    const float* dt     = (const float*)d_in[2];
    const float* mu_p   = (const float*)d_in[3];
    const float* a      = (const float*)d_in[4];
    const float* w      = (const float*)d_in[5];
    const float* phi    = (const float*)d_in[6];
    const float* freq   = (const float*)d_in[7];
    const float* amp    = (const float*)d_in[8];
    const float* phase  = (const float*)d_in[9];
    const float* stdv   = (const float*)d_in[10];
    float* out = (float*)d_out;

    ijspeert_kernel<<<kBlocks, kThreads, 0, stream>>>(
        t, dt, mu_p, a, w, phi, freq, amp, phase, stdv, out);
}